// Round 1
// baseline (762.276 us; speedup 1.0000x reference)
//
#include <hip/hip_runtime.h>

typedef __bf16 bf16;
typedef bf16 bf16x8 __attribute__((ext_vector_type(8)));
typedef float f32x4 __attribute__((ext_vector_type(4)));

#define BB 8
#define TT 8
#define SS 196
#define NTOK 1568           // T*S
#define ROWS 12544          // B*NTOK
#define HH 768
#define HD 64

__device__ __forceinline__ void gload16(const void* g, void* l) {
  __builtin_amdgcn_global_load_lds(
      (const __attribute__((address_space(1))) void*)g,
      (__attribute__((address_space(3))) void*)l, 16, 0, 0);
}

// ---------------- weight transpose f32[K][N] -> bf16[N][K], z-batched -------
__global__ __launch_bounds__(256)
void transpose_w(const float* __restrict__ in, bf16* __restrict__ out, int K, int N) {
  in  += (size_t)blockIdx.z * K * N;
  out += (size_t)blockIdx.z * K * N;
  __shared__ float tile[64][65];
  const int k0 = blockIdx.x * 64, n0 = blockIdx.y * 64;
  const int tx = threadIdx.x & 63, ty = threadIdx.x >> 6;
  #pragma unroll
  for (int rr = ty; rr < 64; rr += 4)
    tile[rr][tx] = in[(size_t)(k0 + rr) * N + n0 + tx];
  __syncthreads();
  #pragma unroll
  for (int rr = ty; rr < 64; rr += 4)
    out[(size_t)(n0 + rr) * K + k0 + tx] = (bf16)tile[tx][rr];
}

// ---------------- layernorm: f32 in -> bf16 out, wave per row ---------------
__global__ __launch_bounds__(256)
void ln_kernel(const float* __restrict__ x, const float* __restrict__ g,
               const float* __restrict__ b, bf16* __restrict__ out) {
  const int row = blockIdx.x * 4 + (threadIdx.x >> 6);
  const int lane = threadIdx.x & 63;
  const float* xr = x + (size_t)row * HH;
  float v[12];
  float sum = 0.f, sq = 0.f;
  #pragma unroll
  for (int i = 0; i < 12; ++i) {
    v[i] = xr[lane + i * 64];
    sum += v[i];
    sq += v[i] * v[i];
  }
  #pragma unroll
  for (int off = 32; off > 0; off >>= 1) {
    sum += __shfl_xor(sum, off);
    sq  += __shfl_xor(sq, off);
  }
  const float mean = sum * (1.f / 768.f);
  const float var = sq * (1.f / 768.f) - mean * mean;
  const float inv = rsqrtf(var + 1e-6f);
  bf16* op = out + (size_t)row * HH;
  #pragma unroll
  for (int i = 0; i < 12; ++i) {
    const int c = lane + i * 64;
    op[c] = (bf16)((v[i] - mean) * inv * g[c] + b[c]);
  }
}

// ---------------- GEMM: C[M,N] = A[M,K](bf16) * BT[N,K](bf16) (+bias)(+resid)
// 128x128 tile, 4 waves, 16x16x32 MFMA, global_load_lds staging.
// MOE: row-gather via perm/descs (tile = 16 n-indices x 8 batch rows).
template<bool MOE, bool BIAS, bool RESID, bool OBF16>
__global__ __launch_bounds__(256)
void gemm_bf16(const bf16* __restrict__ A, const bf16* __restrict__ BT,
               const float* __restrict__ bias, const float* resid,
               float* outF, bf16* outB, int N, int K,
               const int* __restrict__ perm, const int4* __restrict__ descs,
               const int* __restrict__ meta) {
  __shared__ __align__(16) bf16 As[128 * 32];
  __shared__ __align__(16) bf16 Bs[128 * 32];
  __shared__ int rowLds[128];

  int ncnt = 16;
  if constexpr (MOE) {
    if ((int)blockIdx.x >= meta[0]) return;
    int4 d = descs[blockIdx.x];
    BT += (size_t)d.x * N * K;
    ncnt = d.z;
    if (threadIdx.x < 128) {
      const int nl = (int)(threadIdx.x >> 3), b = threadIdx.x & 7;
      const int n = perm[d.y + (nl < ncnt ? nl : ncnt - 1)];
      rowLds[threadIdx.x] = b * NTOK + n;
    }
  } else {
    if (threadIdx.x < 128) rowLds[threadIdx.x] = blockIdx.x * 128 + threadIdx.x;
  }
  __syncthreads();

  const int tid = threadIdx.x;
  const int w = tid >> 6, lane = tid & 63;
  const int wr = w >> 1, wc = w & 1;

  size_t aOff[2], bOff[2];
  int ldsOff[2];
  #pragma unroll
  for (int i = 0; i < 2; ++i) {
    const int e = i * 2048 + w * 512 + lane * 8;
    const int r = e >> 5, kk = e & 31;
    aOff[i] = (size_t)rowLds[r] * K + kk;
    bOff[i] = (size_t)(blockIdx.y * 128 + r) * K + kk;
    ldsOff[i] = i * 2048 + w * 512;
  }

  f32x4 acc[4][4] = {};
  const int lr = lane & 15, kg = (lane >> 4) * 8;

  for (int k0 = 0; k0 < K; k0 += 32) {
    #pragma unroll
    for (int i = 0; i < 2; ++i) {
      gload16(A + aOff[i] + k0, As + ldsOff[i]);
      gload16(BT + bOff[i] + k0, Bs + ldsOff[i]);
    }
    __syncthreads();
    bf16x8 af[4], bv[4];
    #pragma unroll
    for (int m = 0; m < 4; ++m)
      af[m] = *(const bf16x8*)&As[(wr * 64 + m * 16 + lr) * 32 + kg];
    #pragma unroll
    for (int n = 0; n < 4; ++n)
      bv[n] = *(const bf16x8*)&Bs[(wc * 64 + n * 16 + lr) * 32 + kg];
    #pragma unroll
    for (int m = 0; m < 4; ++m)
      #pragma unroll
      for (int n = 0; n < 4; ++n)
        acc[m][n] = __builtin_amdgcn_mfma_f32_16x16x32_bf16(af[m], bv[n], acc[m][n], 0, 0, 0);
    __syncthreads();
  }

  #pragma unroll
  for (int m = 0; m < 4; ++m) {
    #pragma unroll
    for (int j = 0; j < 4; ++j) {
      const int r = wr * 64 + m * 16 + (lane >> 4) * 4 + j;
      if (MOE && ((r >> 3) >= ncnt)) continue;
      const size_t grow = (size_t)rowLds[r];
      #pragma unroll
      for (int n = 0; n < 4; ++n) {
        const int gcol = blockIdx.y * 128 + wc * 64 + n * 16 + lr;
        float v = acc[m][n][j];
        if (BIAS)  v += bias[gcol];
        if (RESID) v += resid[grow * N + gcol];
        if (OBF16) outB[grow * N + gcol] = (bf16)v;
        else       outF[grow * N + gcol] = v;
      }
    }
  }
}

// ---------------- spatial attention: block per (bp, h), S=196, hd=64 --------
__global__ __launch_bounds__(256)
void attn_spatial(const bf16* __restrict__ qkv, bf16* __restrict__ out) {
  __shared__ __align__(16) bf16 Ks[SS * HD];
  __shared__ __align__(16) bf16 Vs[SS * HD];
  const int bp = blockIdx.x, h = blockIdx.y;
  const int tid = threadIdx.x;
  const size_t base = (size_t)bp * SS * 2304 + h * HD;
  for (int idx = tid; idx < SS * HD; idx += 256) {
    const int r = idx >> 6, d = idx & 63;
    const size_t rb = base + (size_t)r * 2304;
    Ks[idx] = qkv[rb + 768 + d];
    Vs[idx] = qkv[rb + 1536 + d];
  }
  __syncthreads();
  if (tid >= SS) return;

  float q[64];
  {
    const bf16x8* qp = (const bf16x8*)(qkv + base + (size_t)tid * 2304);
    #pragma unroll
    for (int j = 0; j < 8; ++j) {
      bf16x8 t = qp[j];
      #pragma unroll
      for (int d = 0; d < 8; ++d) q[j * 8 + d] = (float)t[d];
    }
  }
  float mx = -1e30f, l = 0.f, o[64];
  #pragma unroll
  for (int d = 0; d < 64; ++d) o[d] = 0.f;

  for (int k = 0; k < SS; ++k) {
    const bf16x8* kr = (const bf16x8*)&Ks[k * 64];
    float s = 0.f;
    #pragma unroll
    for (int j = 0; j < 8; ++j) {
      bf16x8 t = kr[j];
      #pragma unroll
      for (int d = 0; d < 8; ++d) s += q[j * 8 + d] * (float)t[d];
    }
    s *= 0.125f;
    const float mn = fmaxf(mx, s);
    const float corr = __expf(mx - mn);
    const float p = __expf(s - mn);
    l = l * corr + p;
    const bf16x8* vr = (const bf16x8*)&Vs[k * 64];
    #pragma unroll
    for (int j = 0; j < 8; ++j) {
      bf16x8 t = vr[j];
      #pragma unroll
      for (int d = 0; d < 8; ++d) o[j * 8 + d] = o[j * 8 + d] * corr + p * (float)t[d];
    }
    mx = mn;
  }
  const float inv = 1.f / l;
  bf16* op = out + ((size_t)bp * SS + tid) * 768 + h * HD;
  #pragma unroll
  for (int d = 0; d < 64; ++d) op[d] = (bf16)(o[d] * inv);
}

// ---------------- temporal attention: wave per (b, s, h), T=8 ---------------
__global__ __launch_bounds__(256)
void attn_temporal(const bf16* __restrict__ qkv, bf16* __restrict__ out) {
  const int pair = blockIdx.x * 4 + (threadIdx.x >> 6);  // (b*196+s)*12 + h
  const int lane = threadIdx.x & 63;
  const int h = pair % 12;
  const int bs = pair / 12;
  const int b = bs / SS, s = bs - b * SS;
  const size_t row0 = (size_t)b * NTOK + s;  // + t*SS
  const int q = lane >> 3, k = lane & 7;
  const bf16* qr = qkv + (row0 + (size_t)q * SS) * 2304 + h * HD;
  const bf16* kr = qkv + (row0 + (size_t)k * SS) * 2304 + 768 + h * HD;
  float sc = 0.f;
  #pragma unroll
  for (int j = 0; j < 8; ++j) {
    bf16x8 qv = ((const bf16x8*)qr)[j];
    bf16x8 kv = ((const bf16x8*)kr)[j];
    #pragma unroll
    for (int d = 0; d < 8; ++d) sc += (float)qv[d] * (float)kv[d];
  }
  sc *= 0.125f;
  float mxv = sc;
  #pragma unroll
  for (int off = 1; off < 8; off <<= 1) mxv = fmaxf(mxv, __shfl_xor(mxv, off));
  float p = __expf(sc - mxv);
  float sum = p;
  #pragma unroll
  for (int off = 1; off < 8; off <<= 1) sum += __shfl_xor(sum, off);
  p /= sum;

  const int dg = lane & 7;
  float o[8] = {0, 0, 0, 0, 0, 0, 0, 0};
  #pragma unroll
  for (int kk = 0; kk < 8; ++kk) {
    const float pk = __shfl(p, (lane & 56) + kk);
    const bf16* vr = qkv + (row0 + (size_t)kk * SS) * 2304 + 1536 + h * HD + dg * 8;
    bf16x8 vv = *(const bf16x8*)vr;
    #pragma unroll
    for (int j = 0; j < 8; ++j) o[j] += pk * (float)vv[j];
  }
  bf16* op = out + (row0 + (size_t)q * SS) * 768 + h * HD + dg * 8;
  bf16x8 ov;
  #pragma unroll
  for (int j = 0; j < 8; ++j) ov[j] = (bf16)o[j];
  *(bf16x8*)op = ov;
}

// ---------------- MoE: bucket n-indices by expert + tile descriptors --------
__global__ __launch_bounds__(256)
void sort_moe(const int* __restrict__ eids, int* __restrict__ perm,
              int4* __restrict__ descs, int* __restrict__ meta) {
  __shared__ int cnt[4], base[4], cur[4];
  const int tid = threadIdx.x;
  if (tid < 4) cnt[tid] = 0;
  __syncthreads();
  for (int n = tid; n < NTOK; n += 256) atomicAdd(&cnt[eids[n]], 1);
  __syncthreads();
  if (tid == 0) {
    int off = 0;
    for (int e = 0; e < 4; ++e) { base[e] = off; cur[e] = off; off += cnt[e]; }
  }
  __syncthreads();
  for (int n = tid; n < NTOK; n += 256) {
    const int pos = atomicAdd(&cur[eids[n]], 1);
    perm[pos] = n;
  }
  if (tid == 0) {
    int t = 0;
    for (int e = 0; e < 4; ++e)
      for (int st = 0; st < cnt[e]; st += 16) {
        const int c = cnt[e] - st;
        descs[t++] = make_int4(e, base[e] + st, c < 16 ? c : 16, 0);
      }
    meta[0] = t;
  }
}

// ---------------- silu(gate)*up ----------------------------------------------
__global__ __launch_bounds__(256)
void silu_mul(const bf16* __restrict__ gu, bf16* __restrict__ out) {
  const size_t i = ((size_t)blockIdx.x * 256 + threadIdx.x) * 4;
  if (i >= (size_t)ROWS * 768) return;
  const size_t row = i / 768, c = i - row * 768;
  const bf16* g = gu + row * 1536 + c;
  const bf16* u = gu + row * 1536 + 768 + c;
  bf16* o = out + i;
  #pragma unroll
  for (int j = 0; j < 4; ++j) {
    const float gv = (float)g[j], uv = (float)u[j];
    const float sv = gv / (1.f + __expf(-gv));
    o[j] = (bf16)(sv * uv);
  }
}

// ---------------- launch ------------------------------------------------------
extern "C" void kernel_launch(void* const* d_in, const int* in_sizes, int n_in,
                              void* d_out, int out_size, void* d_ws, size_t ws_size,
                              hipStream_t stream) {
  (void)in_sizes; (void)n_in; (void)out_size; (void)ws_size;
  const float* x        = (const float*)d_in[0];
  const float* qkv_w_s  = (const float*)d_in[1];
  const float* qkv_b_s  = (const float*)d_in[2];
  const float* proj_w_s = (const float*)d_in[3];
  const float* proj_b_s = (const float*)d_in[4];
  const float* qkv_w_t  = (const float*)d_in[5];
  const float* qkv_b_t  = (const float*)d_in[6];
  const float* proj_w_t = (const float*)d_in[7];
  const float* proj_b_t = (const float*)d_in[8];
  const float* ln_s_g   = (const float*)d_in[9];
  const float* ln_s_b   = (const float*)d_in[10];
  const float* ln_t_g   = (const float*)d_in[11];
  const float* ln_t_b   = (const float*)d_in[12];
  const float* ln_m_g   = (const float*)d_in[13];
  const float* ln_m_b   = (const float*)d_in[14];
  const float* gate_up  = (const float*)d_in[15];
  const float* down_w   = (const float*)d_in[16];
  const int* expert_ids = (const int*)d_in[19];
  float* out = (float*)d_out;

  char* ws = (char*)d_ws;
  bf16* qkvsT   = (bf16*)(ws + 0);
  bf16* projsT  = (bf16*)(ws + 3538944);
  bf16* qkvtT   = (bf16*)(ws + 4718592);
  bf16* projtT  = (bf16*)(ws + 8257536);
  bf16* guT     = (bf16*)(ws + 9437184);
  bf16* downT   = (bf16*)(ws + 18874368);
  bf16* lnbuf   = (bf16*)(ws + 23592960);
  bf16* qkvbuf  = (bf16*)(ws + 42860544);   // also reused as gu (12544x1536)
  bf16* attnbuf = (bf16*)(ws + 100663296);
  float* x1     = (float*)(ws + 119930880);
  int*  perm    = (int*)(ws + 158466048);
  int4* descs   = (int4*)(ws + 158472320);
  int*  meta    = (int*)(ws + 158473952);

  const dim3 blk(256);

  transpose_w<<<dim3(12, 36, 1), blk, 0, stream>>>(qkv_w_s, qkvsT, 768, 2304);
  transpose_w<<<dim3(12, 12, 1), blk, 0, stream>>>(proj_w_s, projsT, 768, 768);
  transpose_w<<<dim3(12, 36, 1), blk, 0, stream>>>(qkv_w_t, qkvtT, 768, 2304);
  transpose_w<<<dim3(12, 12, 1), blk, 0, stream>>>(proj_w_t, projtT, 768, 768);
  transpose_w<<<dim3(12, 24, 4), blk, 0, stream>>>(gate_up, guT, 768, 1536);
  transpose_w<<<dim3(12, 12, 4), blk, 0, stream>>>(down_w, downT, 768, 768);

  // stage 1: spatial
  ln_kernel<<<3136, blk, 0, stream>>>(x, ln_s_g, ln_s_b, lnbuf);
  gemm_bf16<false, true, false, true><<<dim3(98, 18), blk, 0, stream>>>(
      lnbuf, qkvsT, qkv_b_s, nullptr, nullptr, qkvbuf, 2304, 768, nullptr, nullptr, nullptr);
  attn_spatial<<<dim3(64, 12), blk, 0, stream>>>(qkvbuf, attnbuf);
  gemm_bf16<false, true, true, false><<<dim3(98, 6), blk, 0, stream>>>(
      attnbuf, projsT, proj_b_s, x, x1, nullptr, 768, 768, nullptr, nullptr, nullptr);

  // stage 2: temporal
  ln_kernel<<<3136, blk, 0, stream>>>(x1, ln_t_g, ln_t_b, lnbuf);
  gemm_bf16<false, true, false, true><<<dim3(98, 18), blk, 0, stream>>>(
      lnbuf, qkvtT, qkv_b_t, nullptr, nullptr, qkvbuf, 2304, 768, nullptr, nullptr, nullptr);
  attn_temporal<<<4704, blk, 0, stream>>>(qkvbuf, attnbuf);
  gemm_bf16<false, true, true, false><<<dim3(98, 6), blk, 0, stream>>>(
      attnbuf, projtT, proj_b_t, x1, out, nullptr, 768, 768, nullptr, nullptr, nullptr);

  // stage 3: MoE MLP
  ln_kernel<<<3136, blk, 0, stream>>>(out, ln_m_g, ln_m_b, lnbuf);
  sort_moe<<<1, blk, 0, stream>>>(expert_ids, perm, descs, meta);
  gemm_bf16<true, false, false, true><<<dim3(102, 12), blk, 0, stream>>>(
      lnbuf, guT, nullptr, nullptr, nullptr, qkvbuf, 1536, 768, perm, descs, meta);
  silu_mul<<<9408, blk, 0, stream>>>(qkvbuf, lnbuf);
  gemm_bf16<true, false, true, false><<<dim3(102, 6), blk, 0, stream>>>(
      lnbuf, downT, nullptr, out, out, nullptr, 768, 768, perm, descs, meta);
}

// Round 2
// 505.616 us; speedup vs baseline: 1.5076x; 1.5076x over previous
//
#include <hip/hip_runtime.h>

typedef __bf16 bf16;
typedef bf16 bf16x8 __attribute__((ext_vector_type(8)));
typedef float f32x4 __attribute__((ext_vector_type(4)));

#define BB 8
#define TT 8
#define SS 196
#define NTOK 1568           // T*S
#define ROWS 12544          // B*NTOK
#define HH 768
#define HD 64

__device__ __forceinline__ void gload16(const void* g, void* l) {
  __builtin_amdgcn_global_load_lds(
      (const __attribute__((address_space(1))) void*)g,
      (__attribute__((address_space(3))) void*)l, 16, 0, 0);
}

// ---------------- weight transpose f32[K][N] -> bf16[N][K], z-batched -------
__global__ __launch_bounds__(256)
void transpose_w(const float* __restrict__ in, bf16* __restrict__ out, int K, int N) {
  in  += (size_t)blockIdx.z * K * N;
  out += (size_t)blockIdx.z * K * N;
  __shared__ float tile[64][65];
  const int k0 = blockIdx.x * 64, n0 = blockIdx.y * 64;
  const int tx = threadIdx.x & 63, ty = threadIdx.x >> 6;
  #pragma unroll
  for (int rr = ty; rr < 64; rr += 4)
    tile[rr][tx] = in[(size_t)(k0 + rr) * N + n0 + tx];
  __syncthreads();
  #pragma unroll
  for (int rr = ty; rr < 64; rr += 4)
    out[(size_t)(n0 + rr) * K + k0 + tx] = (bf16)tile[tx][rr];
}

// ---------------- layernorm: f32 in -> bf16 out, wave per row ---------------
__global__ __launch_bounds__(256)
void ln_kernel(const float* __restrict__ x, const float* __restrict__ g,
               const float* __restrict__ b, bf16* __restrict__ out) {
  const int row = blockIdx.x * 4 + (threadIdx.x >> 6);
  const int lane = threadIdx.x & 63;
  const float* xr = x + (size_t)row * HH;
  float v[12];
  float sum = 0.f, sq = 0.f;
  #pragma unroll
  for (int i = 0; i < 12; ++i) {
    v[i] = xr[lane + i * 64];
    sum += v[i];
    sq += v[i] * v[i];
  }
  #pragma unroll
  for (int off = 32; off > 0; off >>= 1) {
    sum += __shfl_xor(sum, off);
    sq  += __shfl_xor(sq, off);
  }
  const float mean = sum * (1.f / 768.f);
  const float var = sq * (1.f / 768.f) - mean * mean;
  const float inv = rsqrtf(var + 1e-6f);
  bf16* op = out + (size_t)row * HH;
  #pragma unroll
  for (int i = 0; i < 12; ++i) {
    const int c = lane + i * 64;
    op[c] = (bf16)((v[i] - mean) * inv * g[c] + b[c]);
  }
}

// ---------------- GEMM: C[M,N] = A[M,K](bf16) * BT[N,K](bf16) (+bias)(+resid)
template<bool MOE, bool BIAS, bool RESID, bool OBF16>
__global__ __launch_bounds__(256)
void gemm_bf16(const bf16* __restrict__ A, const bf16* __restrict__ BT,
               const float* __restrict__ bias, const float* resid,
               float* outF, bf16* outB, int N, int K,
               const int* __restrict__ perm, const int4* __restrict__ descs,
               const int* __restrict__ meta) {
  __shared__ __align__(16) bf16 As[128 * 32];
  __shared__ __align__(16) bf16 Bs[128 * 32];
  __shared__ int rowLds[128];

  int ncnt = 16;
  if constexpr (MOE) {
    if ((int)blockIdx.x >= meta[0]) return;
    int4 d = descs[blockIdx.x];
    BT += (size_t)d.x * N * K;
    ncnt = d.z;
    if (threadIdx.x < 128) {
      const int nl = (int)(threadIdx.x >> 3), b = threadIdx.x & 7;
      const int n = perm[d.y + (nl < ncnt ? nl : ncnt - 1)];
      rowLds[threadIdx.x] = b * NTOK + n;
    }
  } else {
    if (threadIdx.x < 128) rowLds[threadIdx.x] = blockIdx.x * 128 + threadIdx.x;
  }
  __syncthreads();

  const int tid = threadIdx.x;
  const int w = tid >> 6, lane = tid & 63;
  const int wr = w >> 1, wc = w & 1;

  size_t aOff[2], bOff[2];
  int ldsOff[2];
  #pragma unroll
  for (int i = 0; i < 2; ++i) {
    const int e = i * 2048 + w * 512 + lane * 8;
    const int r = e >> 5, kk = e & 31;
    aOff[i] = (size_t)rowLds[r] * K + kk;
    bOff[i] = (size_t)(blockIdx.y * 128 + r) * K + kk;
    ldsOff[i] = i * 2048 + w * 512;
  }

  f32x4 acc[4][4] = {};
  const int lr = lane & 15, kg = (lane >> 4) * 8;

  for (int k0 = 0; k0 < K; k0 += 32) {
    #pragma unroll
    for (int i = 0; i < 2; ++i) {
      gload16(A + aOff[i] + k0, As + ldsOff[i]);
      gload16(BT + bOff[i] + k0, Bs + ldsOff[i]);
    }
    __syncthreads();
    bf16x8 af[4], bv[4];
    #pragma unroll
    for (int m = 0; m < 4; ++m)
      af[m] = *(const bf16x8*)&As[(wr * 64 + m * 16 + lr) * 32 + kg];
    #pragma unroll
    for (int n = 0; n < 4; ++n)
      bv[n] = *(const bf16x8*)&Bs[(wc * 64 + n * 16 + lr) * 32 + kg];
    #pragma unroll
    for (int m = 0; m < 4; ++m)
      #pragma unroll
      for (int n = 0; n < 4; ++n)
        acc[m][n] = __builtin_amdgcn_mfma_f32_16x16x32_bf16(af[m], bv[n], acc[m][n], 0, 0, 0);
    __syncthreads();
  }

  #pragma unroll
  for (int m = 0; m < 4; ++m) {
    #pragma unroll
    for (int j = 0; j < 4; ++j) {
      const int r = wr * 64 + m * 16 + (lane >> 4) * 4 + j;
      if (MOE && ((r >> 3) >= ncnt)) continue;
      const size_t grow = (size_t)rowLds[r];
      #pragma unroll
      for (int n = 0; n < 4; ++n) {
        const int gcol = blockIdx.y * 128 + wc * 64 + n * 16 + lr;
        float v = acc[m][n][j];
        if (BIAS)  v += bias[gcol];
        if (RESID) v += resid[grow * N + gcol];
        if (OBF16) outB[grow * N + gcol] = (bf16)v;
        else       outF[grow * N + gcol] = v;
      }
    }
  }
}

// ---------------- spatial attention (MFMA): block per (bp, h), 8 waves ------
// K staged [208][64] bf16 via global_load_lds, chunk-XOR swizzle (src-side).
// V staged transposed Vt[64][232]. Per wave: 16 q-rows, full 208-wide scores
// in regs, softmax, P -> per-wave LDS [16][232] (cols>=208 zeroed), PV MFMA.
#define SPAD 208   // keys padded to 13*16
#define VST 232    // Vt / P row stride (2-way bank safe)
__global__ __launch_bounds__(512)
void attn_spatial(const bf16* __restrict__ qkv, bf16* __restrict__ out) {
  __shared__ __align__(16) bf16 Ks[SPAD * 64];
  __shared__ __align__(16) bf16 Vt[64 * VST];
  __shared__ __align__(16) bf16 Pb[8][16 * VST];

  const int bp = blockIdx.x, h = blockIdx.y;
  const int tid = threadIdx.x;
  const int w = tid >> 6, lane = tid & 63;
  const int lr = lane & 15, lg = lane >> 4;
  const size_t base = (size_t)bp * SS * 2304 + h * HD;

  // --- stage K: 208 rows x 8 chunks(16B); src col pre-swizzled by row&7 ----
  for (int cb = w * 64; cb < SPAD * 8; cb += 512) {
    const int c = cb + lane;
    const int row = c >> 3, seg = c & 7;
    const int srow = row < SS ? row : SS - 1;
    const int sseg = seg ^ (row & 7);
    gload16(qkv + base + (size_t)srow * 2304 + 768 + sseg * 8, Ks + cb * 8);
  }
  // --- stage V transposed: task = (key, dseg) -----------------------------
  for (int t = tid; t < 224 * 8; t += 512) {
    const int k = t >> 3, dseg = t & 7;
    const int sk = k < SS ? k : SS - 1;
    bf16x8 v = *(const bf16x8*)(qkv + base + (size_t)sk * 2304 + 1536 + dseg * 8);
    #pragma unroll
    for (int i = 0; i < 8; ++i) Vt[(dseg * 8 + i) * VST + k] = v[i];
  }
  // --- zero P pad cols 208..223 (per wave) --------------------------------
  bf16* Pw = Pb[w];
  for (int i = lane; i < 256; i += 64)
    Pw[(i >> 4) * VST + 208 + (i & 15)] = (bf16)0.f;
  __syncthreads();

  // --- per-wave q-tiles ----------------------------------------------------
  for (int t = w; t < 13; t += 8) {
    const int q0 = t * 16;
    const int qr = q0 + lr;
    const bf16* qp = qkv + base + (size_t)(qr < SS ? qr : SS - 1) * 2304 + lg * 8;
    const bf16x8 af0 = *(const bf16x8*)qp;
    const bf16x8 af1 = *(const bf16x8*)(qp + 32);

    // scores S[16][208]
    f32x4 sc[13];
    #pragma unroll
    for (int f = 0; f < 13; ++f) sc[f] = (f32x4){0.f, 0.f, 0.f, 0.f};
    #pragma unroll
    for (int f = 0; f < 13; ++f) {
      const int key = f * 16 + lr;
      const bf16x8 bv0 = *(const bf16x8*)&Ks[key * 64 + ((lg) ^ (key & 7)) * 8];
      const bf16x8 bv1 = *(const bf16x8*)&Ks[key * 64 + ((4 + lg) ^ (key & 7)) * 8];
      sc[f] = __builtin_amdgcn_mfma_f32_16x16x32_bf16(af0, bv0, sc[f], 0, 0, 0);
      sc[f] = __builtin_amdgcn_mfma_f32_16x16x32_bf16(af1, bv1, sc[f], 0, 0, 0);
    }
    // scale + mask tail cols
    #pragma unroll
    for (int f = 0; f < 13; ++f)
      #pragma unroll
      for (int j = 0; j < 4; ++j) sc[f][j] *= 0.125f;
    if (192 + lr >= SS)
      #pragma unroll
      for (int j = 0; j < 4; ++j) sc[12][j] = -1e30f;

    // softmax over cols (13 frags in-lane + 16-lane group reduce)
    float mx[4], ls[4];
    #pragma unroll
    for (int j = 0; j < 4; ++j) {
      float m = sc[0][j];
      #pragma unroll
      for (int f = 1; f < 13; ++f) m = fmaxf(m, sc[f][j]);
      #pragma unroll
      for (int off = 1; off < 16; off <<= 1) m = fmaxf(m, __shfl_xor(m, off));
      mx[j] = m;
    }
    #pragma unroll
    for (int j = 0; j < 4; ++j) ls[j] = 0.f;
    #pragma unroll
    for (int f = 0; f < 13; ++f) {
      #pragma unroll
      for (int j = 0; j < 4; ++j) {
        const float p = __expf(sc[f][j] - mx[j]);
        ls[j] += p;
        Pw[(lg * 4 + j) * VST + f * 16 + lr] = (bf16)p;
      }
    }
    #pragma unroll
    for (int j = 0; j < 4; ++j) {
      #pragma unroll
      for (int off = 1; off < 16; off <<= 1) ls[j] += __shfl_xor(ls[j], off);
      ls[j] = 1.f / ls[j];
    }

    // PV: O[16][64] = P[16][224] * Vt^T
    f32x4 oacc[4];
    #pragma unroll
    for (int n = 0; n < 4; ++n) oacc[n] = (f32x4){0.f, 0.f, 0.f, 0.f};
    #pragma unroll
    for (int kb = 0; kb < 7; ++kb) {
      const bf16x8 pa = *(const bf16x8*)&Pw[lr * VST + kb * 32 + lg * 8];
      #pragma unroll
      for (int n = 0; n < 4; ++n) {
        const bf16x8 bv = *(const bf16x8*)&Vt[(n * 16 + lr) * VST + kb * 32 + lg * 8];
        oacc[n] = __builtin_amdgcn_mfma_f32_16x16x32_bf16(pa, bv, oacc[n], 0, 0, 0);
      }
    }
    // store
    #pragma unroll
    for (int j = 0; j < 4; ++j) {
      const int row = q0 + lg * 4 + j;
      if (row < SS) {
        bf16* op = out + ((size_t)bp * SS + row) * 768 + h * HD;
        #pragma unroll
        for (int n = 0; n < 4; ++n) op[n * 16 + lr] = (bf16)(oacc[n][j] * ls[j]);
      }
    }
  }
}

// ---------------- temporal attention: wave per (b, s, h), T=8 ---------------
__global__ __launch_bounds__(256)
void attn_temporal(const bf16* __restrict__ qkv, bf16* __restrict__ out) {
  const int pair = blockIdx.x * 4 + (threadIdx.x >> 6);  // (b*196+s)*12 + h
  const int lane = threadIdx.x & 63;
  const int h = pair % 12;
  const int bs = pair / 12;
  const int b = bs / SS, s = bs - b * SS;
  const size_t row0 = (size_t)b * NTOK + s;  // + t*SS
  const int q = lane >> 3, k = lane & 7;
  const bf16* qr = qkv + (row0 + (size_t)q * SS) * 2304 + h * HD;
  const bf16* kr = qkv + (row0 + (size_t)k * SS) * 2304 + 768 + h * HD;
  float sc = 0.f;
  #pragma unroll
  for (int j = 0; j < 8; ++j) {
    bf16x8 qv = ((const bf16x8*)qr)[j];
    bf16x8 kv = ((const bf16x8*)kr)[j];
    #pragma unroll
    for (int d = 0; d < 8; ++d) sc += (float)qv[d] * (float)kv[d];
  }
  sc *= 0.125f;
  float mxv = sc;
  #pragma unroll
  for (int off = 1; off < 8; off <<= 1) mxv = fmaxf(mxv, __shfl_xor(mxv, off));
  float p = __expf(sc - mxv);
  float sum = p;
  #pragma unroll
  for (int off = 1; off < 8; off <<= 1) sum += __shfl_xor(sum, off);
  p /= sum;

  const int dg = lane & 7;
  float o[8] = {0, 0, 0, 0, 0, 0, 0, 0};
  #pragma unroll
  for (int kk = 0; kk < 8; ++kk) {
    const float pk = __shfl(p, (lane & 56) + kk);
    const bf16* vr = qkv + (row0 + (size_t)kk * SS) * 2304 + 1536 + h * HD + dg * 8;
    bf16x8 vv = *(const bf16x8*)vr;
    #pragma unroll
    for (int j = 0; j < 8; ++j) o[j] += pk * (float)vv[j];
  }
  bf16* op = out + (row0 + (size_t)q * SS) * 768 + h * HD + dg * 8;
  bf16x8 ov;
  #pragma unroll
  for (int j = 0; j < 8; ++j) ov[j] = (bf16)o[j];
  *(bf16x8*)op = ov;
}

// ---------------- MoE: bucket n-indices by expert + tile descriptors --------
__global__ __launch_bounds__(256)
void sort_moe(const int* __restrict__ eids, int* __restrict__ perm,
              int4* __restrict__ descs, int* __restrict__ meta) {
  __shared__ int cnt[4], base[4], cur[4];
  const int tid = threadIdx.x;
  if (tid < 4) cnt[tid] = 0;
  __syncthreads();
  for (int n = tid; n < NTOK; n += 256) atomicAdd(&cnt[eids[n]], 1);
  __syncthreads();
  if (tid == 0) {
    int off = 0;
    for (int e = 0; e < 4; ++e) { base[e] = off; cur[e] = off; off += cnt[e]; }
  }
  __syncthreads();
  for (int n = tid; n < NTOK; n += 256) {
    const int pos = atomicAdd(&cur[eids[n]], 1);
    perm[pos] = n;
  }
  if (tid == 0) {
    int t = 0;
    for (int e = 0; e < 4; ++e)
      for (int st = 0; st < cnt[e]; st += 16) {
        const int c = cnt[e] - st;
        descs[t++] = make_int4(e, base[e] + st, c < 16 ? c : 16, 0);
      }
    meta[0] = t;
  }
}

// ---------------- silu(gate)*up ----------------------------------------------
__global__ __launch_bounds__(256)
void silu_mul(const bf16* __restrict__ gu, bf16* __restrict__ out) {
  const size_t i = ((size_t)blockIdx.x * 256 + threadIdx.x) * 4;
  if (i >= (size_t)ROWS * 768) return;
  const size_t row = i / 768, c = i - row * 768;
  const bf16* g = gu + row * 1536 + c;
  const bf16* u = gu + row * 1536 + 768 + c;
  bf16* o = out + i;
  #pragma unroll
  for (int j = 0; j < 4; ++j) {
    const float gv = (float)g[j], uv = (float)u[j];
    const float sv = gv / (1.f + __expf(-gv));
    o[j] = (bf16)(sv * uv);
  }
}

// ---------------- launch ------------------------------------------------------
extern "C" void kernel_launch(void* const* d_in, const int* in_sizes, int n_in,
                              void* d_out, int out_size, void* d_ws, size_t ws_size,
                              hipStream_t stream) {
  (void)in_sizes; (void)n_in; (void)out_size; (void)ws_size;
  const float* x        = (const float*)d_in[0];
  const float* qkv_w_s  = (const float*)d_in[1];
  const float* qkv_b_s  = (const float*)d_in[2];
  const float* proj_w_s = (const float*)d_in[3];
  const float* proj_b_s = (const float*)d_in[4];
  const float* qkv_w_t  = (const float*)d_in[5];
  const float* qkv_b_t  = (const float*)d_in[6];
  const float* proj_w_t = (const float*)d_in[7];
  const float* proj_b_t = (const float*)d_in[8];
  const float* ln_s_g   = (const float*)d_in[9];
  const float* ln_s_b   = (const float*)d_in[10];
  const float* ln_t_g   = (const float*)d_in[11];
  const float* ln_t_b   = (const float*)d_in[12];
  const float* ln_m_g   = (const float*)d_in[13];
  const float* ln_m_b   = (const float*)d_in[14];
  const float* gate_up  = (const float*)d_in[15];
  const float* down_w   = (const float*)d_in[16];
  const int* expert_ids = (const int*)d_in[19];
  float* out = (float*)d_out;

  char* ws = (char*)d_ws;
  bf16* qkvsT   = (bf16*)(ws + 0);
  bf16* projsT  = (bf16*)(ws + 3538944);
  bf16* qkvtT   = (bf16*)(ws + 4718592);
  bf16* projtT  = (bf16*)(ws + 8257536);
  bf16* guT     = (bf16*)(ws + 9437184);
  bf16* downT   = (bf16*)(ws + 18874368);
  bf16* lnbuf   = (bf16*)(ws + 23592960);
  bf16* qkvbuf  = (bf16*)(ws + 42860544);   // also reused as gu (12544x1536)
  bf16* attnbuf = (bf16*)(ws + 100663296);
  float* x1     = (float*)(ws + 119930880);
  int*  perm    = (int*)(ws + 158466048);
  int4* descs   = (int4*)(ws + 158472320);
  int*  meta    = (int*)(ws + 158473952);

  const dim3 blk(256);

  transpose_w<<<dim3(12, 36, 1), blk, 0, stream>>>(qkv_w_s, qkvsT, 768, 2304);
  transpose_w<<<dim3(12, 12, 1), blk, 0, stream>>>(proj_w_s, projsT, 768, 768);
  transpose_w<<<dim3(12, 36, 1), blk, 0, stream>>>(qkv_w_t, qkvtT, 768, 2304);
  transpose_w<<<dim3(12, 12, 1), blk, 0, stream>>>(proj_w_t, projtT, 768, 768);
  transpose_w<<<dim3(12, 24, 4), blk, 0, stream>>>(gate_up, guT, 768, 1536);
  transpose_w<<<dim3(12, 12, 4), blk, 0, stream>>>(down_w, downT, 768, 768);

  // stage 1: spatial
  ln_kernel<<<3136, blk, 0, stream>>>(x, ln_s_g, ln_s_b, lnbuf);
  gemm_bf16<false, true, false, true><<<dim3(98, 18), blk, 0, stream>>>(
      lnbuf, qkvsT, qkv_b_s, nullptr, nullptr, qkvbuf, 2304, 768, nullptr, nullptr, nullptr);
  attn_spatial<<<dim3(64, 12), dim3(512), 0, stream>>>(qkvbuf, attnbuf);
  gemm_bf16<false, true, true, false><<<dim3(98, 6), blk, 0, stream>>>(
      attnbuf, projsT, proj_b_s, x, x1, nullptr, 768, 768, nullptr, nullptr, nullptr);

  // stage 2: temporal
  ln_kernel<<<3136, blk, 0, stream>>>(x1, ln_t_g, ln_t_b, lnbuf);
  gemm_bf16<false, true, false, true><<<dim3(98, 18), blk, 0, stream>>>(
      lnbuf, qkvtT, qkv_b_t, nullptr, nullptr, qkvbuf, 2304, 768, nullptr, nullptr, nullptr);
  attn_temporal<<<4704, blk, 0, stream>>>(qkvbuf, attnbuf);
  gemm_bf16<false, true, true, false><<<dim3(98, 6), blk, 0, stream>>>(
      attnbuf, projtT, proj_b_t, x1, out, nullptr, 768, 768, nullptr, nullptr, nullptr);

  // stage 3: MoE MLP
  ln_kernel<<<3136, blk, 0, stream>>>(out, ln_m_g, ln_m_b, lnbuf);
  sort_moe<<<1, blk, 0, stream>>>(expert_ids, perm, descs, meta);
  gemm_bf16<true, false, false, true><<<dim3(102, 12), blk, 0, stream>>>(
      lnbuf, guT, nullptr, nullptr, nullptr, qkvbuf, 1536, 768, perm, descs, meta);
  silu_mul<<<9408, blk, 0, stream>>>(qkvbuf, lnbuf);
  gemm_bf16<true, false, true, false><<<dim3(102, 6), blk, 0, stream>>>(
      lnbuf, downT, nullptr, out, out, nullptr, 768, 768, perm, descs, meta);
}

// Round 3
// 470.706 us; speedup vs baseline: 1.6194x; 1.0742x over previous
//
#include <hip/hip_runtime.h>

typedef __bf16 bf16;
typedef bf16 bf16x8 __attribute__((ext_vector_type(8)));
typedef float f32x4 __attribute__((ext_vector_type(4)));

#define BB 8
#define TT 8
#define SS 196
#define NTOK 1568           // T*S
#define ROWS 12544          // B*NTOK
#define HH 768
#define HD 64

__device__ __forceinline__ void gload16(const void* g, void* l) {
  __builtin_amdgcn_global_load_lds(
      (const __attribute__((address_space(1))) void*)g,
      (__attribute__((address_space(3))) void*)l, 16, 0, 0);
}

// ---------------- weight transpose f32[K][N] -> bf16[N][K], z-batched -------
__global__ __launch_bounds__(256)
void transpose_w(const float* __restrict__ in, bf16* __restrict__ out, int K, int N) {
  in  += (size_t)blockIdx.z * K * N;
  out += (size_t)blockIdx.z * K * N;
  __shared__ float tile[64][65];
  const int k0 = blockIdx.x * 64, n0 = blockIdx.y * 64;
  const int tx = threadIdx.x & 63, ty = threadIdx.x >> 6;
  #pragma unroll
  for (int rr = ty; rr < 64; rr += 4)
    tile[rr][tx] = in[(size_t)(k0 + rr) * N + n0 + tx];
  __syncthreads();
  #pragma unroll
  for (int rr = ty; rr < 64; rr += 4)
    out[(size_t)(n0 + rr) * K + k0 + tx] = (bf16)tile[tx][rr];
}

// ---------------- layernorm: f32 in -> bf16 out, wave per row ---------------
__global__ __launch_bounds__(256)
void ln_kernel(const float* __restrict__ x, const float* __restrict__ g,
               const float* __restrict__ b, bf16* __restrict__ out) {
  const int row = blockIdx.x * 4 + (threadIdx.x >> 6);
  const int lane = threadIdx.x & 63;
  const float* xr = x + (size_t)row * HH;
  float v[12];
  float sum = 0.f, sq = 0.f;
  #pragma unroll
  for (int i = 0; i < 12; ++i) {
    v[i] = xr[lane + i * 64];
    sum += v[i];
    sq += v[i] * v[i];
  }
  #pragma unroll
  for (int off = 32; off > 0; off >>= 1) {
    sum += __shfl_xor(sum, off);
    sq  += __shfl_xor(sq, off);
  }
  const float mean = sum * (1.f / 768.f);
  const float var = sq * (1.f / 768.f) - mean * mean;
  const float inv = rsqrtf(var + 1e-6f);
  bf16* op = out + (size_t)row * HH;
  #pragma unroll
  for (int i = 0; i < 12; ++i) {
    const int c = lane + i * 64;
    op[c] = (bf16)((v[i] - mean) * inv * g[c] + b[c]);
  }
}

// ---------------- dense GEMM, 256xBN tile, 3-buf deep pipeline --------------
// C[M,N] = A[M,K](bf16) * BT[N,K](bf16) (+bias)(+resid). 512 thr = 8 waves
// (2M x 4N), BK=32, 3 LDS buffers, counted vmcnt (T3+T4), chunk-XOR swizzle
// (T2, both-sides per rule #21), setprio around MFMA (T5).
template<int BN, bool BIAS, bool RESID, bool OBF16>
__global__ __launch_bounds__(512, 2)
void gemm256(const bf16* __restrict__ A, const bf16* __restrict__ BT,
             const float* __restrict__ bias, const float* __restrict__ resid,
             float* __restrict__ outF, bf16* __restrict__ outB,
             int N, int K) {
  constexpr int NF = BN / 64;           // n-frags per wave
  constexpr int BUFE = 8192 + BN * 32;  // elems per buffer (A area + B area)
  constexpr int BR = BN / 128;          // B staging rounds per tile
  constexpr int VW = 2 + BR;            // steady-state vmcnt (loads/stage)
  __shared__ __align__(16) bf16 lds[3 * BUFE];

  const int tid = threadIdx.x;
  const int w = tid >> 6, lane = tid & 63;
  const int wr = w >> 2, wc = w & 3;
  const int lr = lane & 15, lg = lane >> 4;
  const int M0 = blockIdx.x * 256, N0 = blockIdx.y * BN;

  // staging: thread -> (row = r*128 + tid/4, chunk = tid&3), source chunk
  // pre-swizzled by (row>>1)&3 == (tid>>3)&3 (rule #21: linear LDS dest).
  const int cs = ((tid & 3) ^ ((tid >> 3) & 3)) * 8;
  const int srow = tid >> 2;
  const bf16* aS0 = A  + (size_t)(M0 + srow) * K + cs;
  const bf16* aS1 = A  + (size_t)(M0 + 128 + srow) * K + cs;
  const bf16* bS0 = BT + (size_t)(N0 + srow) * K + cs;
  const bf16* bS1 = BT + (size_t)(N0 + 128 + srow) * K + cs;  // BN==256 only
  const int ldsW = w * 512;

  const int NT = K >> 5;

#define STG(tt) { bf16* bp = lds + ((tt) % 3) * BUFE; const int ko = (tt) << 5; \
    gload16(aS0 + ko, bp + ldsW);                                               \
    gload16(aS1 + ko, bp + 4096 + ldsW);                                        \
    gload16(bS0 + ko, bp + 8192 + ldsW);                                        \
    if constexpr (BN == 256) gload16(bS1 + ko, bp + 12288 + ldsW); }

  STG(0);
  STG(1);

  f32x4 acc[8][NF] = {};
  const int xr = ((lr >> 1) & 3) * 8;   // read-side chunk XOR (elements)

  for (int t = 0; t < NT; ++t) {
    if (t + 1 < NT) { asm volatile("s_waitcnt vmcnt(%0)" :: "i"(VW) : "memory"); }
    else            { asm volatile("s_waitcnt vmcnt(0)" ::: "memory"); }
    __builtin_amdgcn_s_barrier();
    asm volatile("" ::: "memory");

    const bf16* Ab = lds + (t % 3) * BUFE;
    const bf16* Bb = Ab + 8192;
    bf16x8 af[8], bf_[NF];
    #pragma unroll
    for (int m = 0; m < 8; ++m)
      af[m] = *(const bf16x8*)&Ab[(wr * 128 + m * 16 + lr) * 32 + ((lg * 8) ^ xr)];
    #pragma unroll
    for (int n = 0; n < NF; ++n)
      bf_[n] = *(const bf16x8*)&Bb[(wc * (BN / 4) + n * 16 + lr) * 32 + ((lg * 8) ^ xr)];

    __builtin_amdgcn_s_setprio(1);
    #pragma unroll
    for (int m = 0; m < 8; ++m)
      #pragma unroll
      for (int n = 0; n < NF; ++n)
        acc[m][n] = __builtin_amdgcn_mfma_f32_16x16x32_bf16(af[m], bf_[n], acc[m][n], 0, 0, 0);
    __builtin_amdgcn_s_setprio(0);

    asm volatile("" ::: "memory");
    __builtin_amdgcn_s_barrier();
    asm volatile("" ::: "memory");
    if (t + 2 < NT) STG(t + 2);
  }
#undef STG

  #pragma unroll
  for (int m = 0; m < 8; ++m) {
    const int grow = M0 + wr * 128 + m * 16 + lg * 4;
    #pragma unroll
    for (int j = 0; j < 4; ++j) {
      const size_t rbase = (size_t)(grow + j) * N;
      #pragma unroll
      for (int n = 0; n < NF; ++n) {
        const int gcol = N0 + wc * (BN / 4) + n * 16 + lr;
        float v = acc[m][n][j];
        if constexpr (BIAS)  v += bias[gcol];
        if constexpr (RESID) v += resid[rbase + gcol];
        if constexpr (OBF16) outB[rbase + gcol] = (bf16)v;
        else                 outF[rbase + gcol] = v;
      }
    }
  }
}

// ---------------- MoE GEMM (gathered rows), 128x128 tile --------------------
template<bool MOE, bool BIAS, bool RESID, bool OBF16>
__global__ __launch_bounds__(256)
void gemm_bf16(const bf16* __restrict__ A, const bf16* __restrict__ BT,
               const float* __restrict__ bias, const float* resid,
               float* outF, bf16* outB, int N, int K,
               const int* __restrict__ perm, const int4* __restrict__ descs,
               const int* __restrict__ meta) {
  __shared__ __align__(16) bf16 As[128 * 32];
  __shared__ __align__(16) bf16 Bs[128 * 32];
  __shared__ int rowLds[128];

  int ncnt = 16;
  if constexpr (MOE) {
    if ((int)blockIdx.x >= meta[0]) return;
    int4 d = descs[blockIdx.x];
    BT += (size_t)d.x * N * K;
    ncnt = d.z;
    if (threadIdx.x < 128) {
      const int nl = (int)(threadIdx.x >> 3), b = threadIdx.x & 7;
      const int n = perm[d.y + (nl < ncnt ? nl : ncnt - 1)];
      rowLds[threadIdx.x] = b * NTOK + n;
    }
  } else {
    if (threadIdx.x < 128) rowLds[threadIdx.x] = blockIdx.x * 128 + threadIdx.x;
  }
  __syncthreads();

  const int tid = threadIdx.x;
  const int w = tid >> 6, lane = tid & 63;
  const int wr = w >> 1, wc = w & 1;

  size_t aOff[2], bOff[2];
  int ldsOff[2];
  #pragma unroll
  for (int i = 0; i < 2; ++i) {
    const int e = i * 2048 + w * 512 + lane * 8;
    const int r = e >> 5, kk = e & 31;
    aOff[i] = (size_t)rowLds[r] * K + kk;
    bOff[i] = (size_t)(blockIdx.y * 128 + r) * K + kk;
    ldsOff[i] = i * 2048 + w * 512;
  }

  f32x4 acc[4][4] = {};
  const int lr = lane & 15, kg = (lane >> 4) * 8;

  for (int k0 = 0; k0 < K; k0 += 32) {
    #pragma unroll
    for (int i = 0; i < 2; ++i) {
      gload16(A + aOff[i] + k0, As + ldsOff[i]);
      gload16(BT + bOff[i] + k0, Bs + ldsOff[i]);
    }
    __syncthreads();
    bf16x8 af[4], bv[4];
    #pragma unroll
    for (int m = 0; m < 4; ++m)
      af[m] = *(const bf16x8*)&As[(wr * 64 + m * 16 + lr) * 32 + kg];
    #pragma unroll
    for (int n = 0; n < 4; ++n)
      bv[n] = *(const bf16x8*)&Bs[(wc * 64 + n * 16 + lr) * 32 + kg];
    #pragma unroll
    for (int m = 0; m < 4; ++m)
      #pragma unroll
      for (int n = 0; n < 4; ++n)
        acc[m][n] = __builtin_amdgcn_mfma_f32_16x16x32_bf16(af[m], bv[n], acc[m][n], 0, 0, 0);
    __syncthreads();
  }

  #pragma unroll
  for (int m = 0; m < 4; ++m) {
    #pragma unroll
    for (int j = 0; j < 4; ++j) {
      const int r = wr * 64 + m * 16 + (lane >> 4) * 4 + j;
      if (MOE && ((r >> 3) >= ncnt)) continue;
      const size_t grow = (size_t)rowLds[r];
      #pragma unroll
      for (int n = 0; n < 4; ++n) {
        const int gcol = blockIdx.y * 128 + wc * 64 + n * 16 + lr;
        float v = acc[m][n][j];
        if (BIAS)  v += bias[gcol];
        if (RESID) v += resid[grow * N + gcol];
        if (OBF16) outB[grow * N + gcol] = (bf16)v;
        else       outF[grow * N + gcol] = v;
      }
    }
  }
}

// ---------------- spatial attention (MFMA): block per (bp, h), 8 waves ------
#define SPAD 208   // keys padded to 13*16
#define VST 232    // Vt / P row stride (2-way bank safe)
__global__ __launch_bounds__(512)
void attn_spatial(const bf16* __restrict__ qkv, bf16* __restrict__ out) {
  __shared__ __align__(16) bf16 Ks[SPAD * 64];
  __shared__ __align__(16) bf16 Vt[64 * VST];
  __shared__ __align__(16) bf16 Pb[8][16 * VST];

  const int bp = blockIdx.x, h = blockIdx.y;
  const int tid = threadIdx.x;
  const int w = tid >> 6, lane = tid & 63;
  const int lr = lane & 15, lg = lane >> 4;
  const size_t base = (size_t)bp * SS * 2304 + h * HD;

  // --- stage K: 208 rows x 8 chunks(16B); src col pre-swizzled by row&7 ----
  for (int cb = w * 64; cb < SPAD * 8; cb += 512) {
    const int c = cb + lane;
    const int row = c >> 3, seg = c & 7;
    const int srow = row < SS ? row : SS - 1;
    const int sseg = seg ^ (row & 7);
    gload16(qkv + base + (size_t)srow * 2304 + 768 + sseg * 8, Ks + cb * 8);
  }
  // --- stage V transposed: task = (key, dseg) -----------------------------
  for (int t = tid; t < 224 * 8; t += 512) {
    const int k = t >> 3, dseg = t & 7;
    const int sk = k < SS ? k : SS - 1;
    bf16x8 v = *(const bf16x8*)(qkv + base + (size_t)sk * 2304 + 1536 + dseg * 8);
    #pragma unroll
    for (int i = 0; i < 8; ++i) Vt[(dseg * 8 + i) * VST + k] = v[i];
  }
  // --- zero P pad cols 208..223 (per wave) --------------------------------
  bf16* Pw = Pb[w];
  for (int i = lane; i < 256; i += 64)
    Pw[(i >> 4) * VST + 208 + (i & 15)] = (bf16)0.f;
  __syncthreads();

  // --- per-wave q-tiles ----------------------------------------------------
  for (int t = w; t < 13; t += 8) {
    const int q0 = t * 16;
    const int qr = q0 + lr;
    const bf16* qp = qkv + base + (size_t)(qr < SS ? qr : SS - 1) * 2304 + lg * 8;
    const bf16x8 af0 = *(const bf16x8*)qp;
    const bf16x8 af1 = *(const bf16x8*)(qp + 32);

    // scores S[16][208]
    f32x4 sc[13];
    #pragma unroll
    for (int f = 0; f < 13; ++f) sc[f] = (f32x4){0.f, 0.f, 0.f, 0.f};
    #pragma unroll
    for (int f = 0; f < 13; ++f) {
      const int key = f * 16 + lr;
      const bf16x8 bv0 = *(const bf16x8*)&Ks[key * 64 + ((lg) ^ (key & 7)) * 8];
      const bf16x8 bv1 = *(const bf16x8*)&Ks[key * 64 + ((4 + lg) ^ (key & 7)) * 8];
      sc[f] = __builtin_amdgcn_mfma_f32_16x16x32_bf16(af0, bv0, sc[f], 0, 0, 0);
      sc[f] = __builtin_amdgcn_mfma_f32_16x16x32_bf16(af1, bv1, sc[f], 0, 0, 0);
    }
    // scale + mask tail cols
    #pragma unroll
    for (int f = 0; f < 13; ++f)
      #pragma unroll
      for (int j = 0; j < 4; ++j) sc[f][j] *= 0.125f;
    if (192 + lr >= SS)
      #pragma unroll
      for (int j = 0; j < 4; ++j) sc[12][j] = -1e30f;

    // softmax over cols (13 frags in-lane + 16-lane group reduce)
    float mx[4], ls[4];
    #pragma unroll
    for (int j = 0; j < 4; ++j) {
      float m = sc[0][j];
      #pragma unroll
      for (int f = 1; f < 13; ++f) m = fmaxf(m, sc[f][j]);
      #pragma unroll
      for (int off = 1; off < 16; off <<= 1) m = fmaxf(m, __shfl_xor(m, off));
      mx[j] = m;
    }
    #pragma unroll
    for (int j = 0; j < 4; ++j) ls[j] = 0.f;
    #pragma unroll
    for (int f = 0; f < 13; ++f) {
      #pragma unroll
      for (int j = 0; j < 4; ++j) {
        const float p = __expf(sc[f][j] - mx[j]);
        ls[j] += p;
        Pw[(lg * 4 + j) * VST + f * 16 + lr] = (bf16)p;
      }
    }
    #pragma unroll
    for (int j = 0; j < 4; ++j) {
      #pragma unroll
      for (int off = 1; off < 16; off <<= 1) ls[j] += __shfl_xor(ls[j], off);
      ls[j] = 1.f / ls[j];
    }

    // PV: O[16][64] = P[16][224] * Vt^T
    f32x4 oacc[4];
    #pragma unroll
    for (int n = 0; n < 4; ++n) oacc[n] = (f32x4){0.f, 0.f, 0.f, 0.f};
    #pragma unroll
    for (int kb = 0; kb < 7; ++kb) {
      const bf16x8 pa = *(const bf16x8*)&Pw[lr * VST + kb * 32 + lg * 8];
      #pragma unroll
      for (int n = 0; n < 4; ++n) {
        const bf16x8 bv = *(const bf16x8*)&Vt[(n * 16 + lr) * VST + kb * 32 + lg * 8];
        oacc[n] = __builtin_amdgcn_mfma_f32_16x16x32_bf16(pa, bv, oacc[n], 0, 0, 0);
      }
    }
    // store
    #pragma unroll
    for (int j = 0; j < 4; ++j) {
      const int row = q0 + lg * 4 + j;
      if (row < SS) {
        bf16* op = out + ((size_t)bp * SS + row) * 768 + h * HD;
        #pragma unroll
        for (int n = 0; n < 4; ++n) op[n * 16 + lr] = (bf16)(oacc[n][j] * ls[j]);
      }
    }
  }
}

// ---------------- temporal attention: wave per (b, s, h), T=8 ---------------
__global__ __launch_bounds__(256)
void attn_temporal(const bf16* __restrict__ qkv, bf16* __restrict__ out) {
  const int pair = blockIdx.x * 4 + (threadIdx.x >> 6);  // (b*196+s)*12 + h
  const int lane = threadIdx.x & 63;
  const int h = pair % 12;
  const int bs = pair / 12;
  const int b = bs / SS, s = bs - b * SS;
  const size_t row0 = (size_t)b * NTOK + s;  // + t*SS
  const int q = lane >> 3, k = lane & 7;
  const bf16* qr = qkv + (row0 + (size_t)q * SS) * 2304 + h * HD;
  const bf16* kr = qkv + (row0 + (size_t)k * SS) * 2304 + 768 + h * HD;
  float sc = 0.f;
  #pragma unroll
  for (int j = 0; j < 8; ++j) {
    bf16x8 qv = ((const bf16x8*)qr)[j];
    bf16x8 kv = ((const bf16x8*)kr)[j];
    #pragma unroll
    for (int d = 0; d < 8; ++d) sc += (float)qv[d] * (float)kv[d];
  }
  sc *= 0.125f;
  float mxv = sc;
  #pragma unroll
  for (int off = 1; off < 8; off <<= 1) mxv = fmaxf(mxv, __shfl_xor(mxv, off));
  float p = __expf(sc - mxv);
  float sum = p;
  #pragma unroll
  for (int off = 1; off < 8; off <<= 1) sum += __shfl_xor(sum, off);
  p /= sum;

  const int dg = lane & 7;
  float o[8] = {0, 0, 0, 0, 0, 0, 0, 0};
  #pragma unroll
  for (int kk = 0; kk < 8; ++kk) {
    const float pk = __shfl(p, (lane & 56) + kk);
    const bf16* vr = qkv + (row0 + (size_t)kk * SS) * 2304 + 1536 + h * HD + dg * 8;
    bf16x8 vv = *(const bf16x8*)vr;
    #pragma unroll
    for (int j = 0; j < 8; ++j) o[j] += pk * (float)vv[j];
  }
  bf16* op = out + (row0 + (size_t)q * SS) * 768 + h * HD + dg * 8;
  bf16x8 ov;
  #pragma unroll
  for (int j = 0; j < 8; ++j) ov[j] = (bf16)o[j];
  *(bf16x8*)op = ov;
}

// ---------------- MoE: bucket n-indices by expert + tile descriptors --------
__global__ __launch_bounds__(256)
void sort_moe(const int* __restrict__ eids, int* __restrict__ perm,
              int4* __restrict__ descs, int* __restrict__ meta) {
  __shared__ int cnt[4], base[4], cur[4];
  const int tid = threadIdx.x;
  if (tid < 4) cnt[tid] = 0;
  __syncthreads();
  for (int n = tid; n < NTOK; n += 256) atomicAdd(&cnt[eids[n]], 1);
  __syncthreads();
  if (tid == 0) {
    int off = 0;
    for (int e = 0; e < 4; ++e) { base[e] = off; cur[e] = off; off += cnt[e]; }
  }
  __syncthreads();
  for (int n = tid; n < NTOK; n += 256) {
    const int pos = atomicAdd(&cur[eids[n]], 1);
    perm[pos] = n;
  }
  if (tid == 0) {
    int t = 0;
    for (int e = 0; e < 4; ++e)
      for (int st = 0; st < cnt[e]; st += 16) {
        const int c = cnt[e] - st;
        descs[t++] = make_int4(e, base[e] + st, c < 16 ? c : 16, 0);
      }
    meta[0] = t;
  }
}

// ---------------- silu(gate)*up ----------------------------------------------
__global__ __launch_bounds__(256)
void silu_mul(const bf16* __restrict__ gu, bf16* __restrict__ out) {
  const size_t i = ((size_t)blockIdx.x * 256 + threadIdx.x) * 4;
  if (i >= (size_t)ROWS * 768) return;
  const size_t row = i / 768, c = i - row * 768;
  const bf16* g = gu + row * 1536 + c;
  const bf16* u = gu + row * 1536 + 768 + c;
  bf16* o = out + i;
  #pragma unroll
  for (int j = 0; j < 4; ++j) {
    const float gv = (float)g[j], uv = (float)u[j];
    const float sv = gv / (1.f + __expf(-gv));
    o[j] = (bf16)(sv * uv);
  }
}

// ---------------- launch ------------------------------------------------------
extern "C" void kernel_launch(void* const* d_in, const int* in_sizes, int n_in,
                              void* d_out, int out_size, void* d_ws, size_t ws_size,
                              hipStream_t stream) {
  (void)in_sizes; (void)n_in; (void)out_size; (void)ws_size;
  const float* x        = (const float*)d_in[0];
  const float* qkv_w_s  = (const float*)d_in[1];
  const float* qkv_b_s  = (const float*)d_in[2];
  const float* proj_w_s = (const float*)d_in[3];
  const float* proj_b_s = (const float*)d_in[4];
  const float* qkv_w_t  = (const float*)d_in[5];
  const float* qkv_b_t  = (const float*)d_in[6];
  const float* proj_w_t = (const float*)d_in[7];
  const float* proj_b_t = (const float*)d_in[8];
  const float* ln_s_g   = (const float*)d_in[9];
  const float* ln_s_b   = (const float*)d_in[10];
  const float* ln_t_g   = (const float*)d_in[11];
  const float* ln_t_b   = (const float*)d_in[12];
  const float* ln_m_g   = (const float*)d_in[13];
  const float* ln_m_b   = (const float*)d_in[14];
  const float* gate_up  = (const float*)d_in[15];
  const float* down_w   = (const float*)d_in[16];
  const int* expert_ids = (const int*)d_in[19];
  float* out = (float*)d_out;

  char* ws = (char*)d_ws;
  bf16* qkvsT   = (bf16*)(ws + 0);
  bf16* projsT  = (bf16*)(ws + 3538944);
  bf16* qkvtT   = (bf16*)(ws + 4718592);
  bf16* projtT  = (bf16*)(ws + 8257536);
  bf16* guT     = (bf16*)(ws + 9437184);
  bf16* downT   = (bf16*)(ws + 18874368);
  bf16* lnbuf   = (bf16*)(ws + 23592960);
  bf16* qkvbuf  = (bf16*)(ws + 42860544);   // also reused as gu (12544x1536)
  bf16* attnbuf = (bf16*)(ws + 100663296);
  float* x1     = (float*)(ws + 119930880);
  int*  perm    = (int*)(ws + 158466048);
  int4* descs   = (int4*)(ws + 158472320);
  int*  meta    = (int*)(ws + 158473952);

  const dim3 blk(256);
  const dim3 blk512(512);

  transpose_w<<<dim3(12, 36, 1), blk, 0, stream>>>(qkv_w_s, qkvsT, 768, 2304);
  transpose_w<<<dim3(12, 12, 1), blk, 0, stream>>>(proj_w_s, projsT, 768, 768);
  transpose_w<<<dim3(12, 36, 1), blk, 0, stream>>>(qkv_w_t, qkvtT, 768, 2304);
  transpose_w<<<dim3(12, 12, 1), blk, 0, stream>>>(proj_w_t, projtT, 768, 768);
  transpose_w<<<dim3(12, 24, 4), blk, 0, stream>>>(gate_up, guT, 768, 1536);
  transpose_w<<<dim3(12, 12, 4), blk, 0, stream>>>(down_w, downT, 768, 768);

  // stage 1: spatial
  ln_kernel<<<3136, blk, 0, stream>>>(x, ln_s_g, ln_s_b, lnbuf);
  gemm256<256, true, false, true><<<dim3(49, 9), blk512, 0, stream>>>(
      lnbuf, qkvsT, qkv_b_s, nullptr, nullptr, qkvbuf, 2304, 768);
  attn_spatial<<<dim3(64, 12), blk512, 0, stream>>>(qkvbuf, attnbuf);
  gemm256<128, true, true, false><<<dim3(49, 6), blk512, 0, stream>>>(
      attnbuf, projsT, proj_b_s, x, x1, nullptr, 768, 768);

  // stage 2: temporal
  ln_kernel<<<3136, blk, 0, stream>>>(x1, ln_t_g, ln_t_b, lnbuf);
  gemm256<256, true, false, true><<<dim3(49, 9), blk512, 0, stream>>>(
      lnbuf, qkvtT, qkv_b_t, nullptr, nullptr, qkvbuf, 2304, 768);
  attn_temporal<<<4704, blk, 0, stream>>>(qkvbuf, attnbuf);
  gemm256<128, true, true, false><<<dim3(49, 6), blk512, 0, stream>>>(
      attnbuf, projtT, proj_b_t, x1, out, nullptr, 768, 768);

  // stage 3: MoE MLP
  ln_kernel<<<3136, blk, 0, stream>>>(out, ln_m_g, ln_m_b, lnbuf);
  sort_moe<<<1, blk, 0, stream>>>(expert_ids, perm, descs, meta);
  gemm_bf16<true, false, false, true><<<dim3(102, 12), blk, 0, stream>>>(
      lnbuf, guT, nullptr, nullptr, nullptr, qkvbuf, 1536, 768, perm, descs, meta);
  silu_mul<<<9408, blk, 0, stream>>>(qkvbuf, lnbuf);
  gemm_bf16<true, false, true, false><<<dim3(102, 6), blk, 0, stream>>>(
      lnbuf, downT, nullptr, out, out, nullptr, 768, 768, perm, descs, meta);
}